// Round 5
// baseline (133.873 us; speedup 1.0000x reference)
//
#include <hip/hip_runtime.h>

#define MD 4
#define DD 9          // 2*MD+1
#define KK 81         // DD*DD
#define B_ 4
#define C_ 128
#define H_ 192
#define W_ 192
#define HW (H_ * W_)
#define NWG 4608      // 2 chalf * 3 xt * 192 y * 4 b
#define PER_XCD (NWG / 8)

// out[b,c,y,x] = (1/C) * sum_{p,o} first[b,p*9+o,y,x] * second[b,c,y+p-4,x+o-4]
//
// Block: 256 thr = 16 xg (x-vec4) x 16 cg (4 ch each) -> 64 ch, 64 x, 1 y.
// Grid 4608 = 2 ch-halves x 3 x-tiles x 192 y x 4 b, XCD-swizzled y-fastest.
//
// Round-5 trims (round 4: VALU-busy ~50us vs ~25us FMA floor, dur 90.6us):
//  - X-edge handling folded into the WEIGHTS at stage time: ldsF[k][xl]
//    multiplies second[x = xt0+xl+(k%9)-4]; zero it once if that x is OOB.
//    Deletes 288 cndmask/thread in 2/3 of blocks + the edge branch.
//    (s-loads at edges are clamped in-bounds -> garbage * 0 = correct.)
//  - 32-bit voffset addressing off a uniform base (12 v_add_u32/p, uniform
//    row-advance in SALU) instead of per-lane 64-bit pointer math.
//  - Pipeline unchanged: h(p) loads -> FMA g(p) -> g(p+1) loads -> FMA h(p).
// (256,1): no VGPR pin (spill sentinel: WRITE_SIZE must stay == 73728 KB).

#define LD(off) (*reinterpret_cast<const float4*>(secB + (off)))

#define FMA_GRP(acc, A, M, E)                                          \
  {                                                                    \
    float s_[12] = {A.x, A.y, A.z, A.w, M.x, M.y, M.z, M.w,            \
                    E.x, E.y, E.z, E.w};                               \
    _Pragma("unroll")                                                  \
    for (int o = 0; o < DD; ++o) {                                     \
      acc[0] = fmaf(fo[o].x, s_[o + 0], acc[0]);                       \
      acc[1] = fmaf(fo[o].y, s_[o + 1], acc[1]);                       \
      acc[2] = fmaf(fo[o].z, s_[o + 2], acc[2]);                       \
      acc[3] = fmaf(fo[o].w, s_[o + 3], acc[3]);                       \
    }                                                                  \
  }

__global__ __launch_bounds__(256, 1)
void corr_transpose_kernel(const float* __restrict__ first,
                           const float* __restrict__ second,
                           float* __restrict__ out) {
  __shared__ __align__(16) float ldsF[KK * 64];

  // bijective XCD swizzle (4608 % 8 == 0), y-fastest within an XCD chunk
  const int lin = blockIdx.x;
  const int wid = (lin & 7) * PER_XCD + (lin >> 3);
  const int y     = wid % H_;
  const int t     = wid / H_;          // 0..23
  const int chalf = t & 1;
  const int xt0   = ((t >> 1) % 3) * 64;
  const int b     = t / 6;

  const int tid = threadIdx.x;

  // ---- stage first[b,:,y,xt0..+63] into LDS with X-edge weight masking ----
  {
    const float* fbase = first + ((size_t)(b * KK) * H_ + y) * (size_t)W_ + xt0;
    const bool edge = (xt0 != 64);     // block-uniform
    for (int idx = tid; idx < KK * 16; idx += 256) {
      const int k  = idx >> 4;
      const int xi = (idx & 15) << 2;
      float4 v = *reinterpret_cast<const float4*>(fbase + (size_t)k * HW + xi);
      if (edge) {
        const int o    = k % DD;
        const int base = xt0 + xi + o - MD;   // second-x for component 0
        if (base + 0 < 0 || base + 0 >= W_) v.x = 0.f;
        if (base + 1 < 0 || base + 1 >= W_) v.y = 0.f;
        if (base + 2 < 0 || base + 2 >= W_) v.z = 0.f;
        if (base + 3 < 0 || base + 3 >= W_) v.w = 0.f;
      }
      *reinterpret_cast<float4*>(&ldsF[k * 64 + xi]) = v;
    }
  }

  const int xg = tid & 15;
  const int cg = tid >> 4;
  const int c0 = chalf * 64 + cg * 4;
  const int x0 = xt0 + xg * 4;

  // p-loop bounds hoisted (block-uniform); X handled by weight masking
  const int pstart = (y >= MD) ? 0 : (MD - y);
  const int pend   = (y + MD < H_) ? DD : (H_ + MD - y);
  const int yy0    = y + pstart - MD;

  const char* secB = (const char*)(second + (size_t)b * C_ * HW);

  // 32-bit byte offsets; A/E clamped in-bounds when the tile touches an edge
  // (their weights are zeroed in LDS, so clamped data is harmless).
  const bool mA = (x0 != 0);
  const bool mE = (x0 + 8 <= W_);
  int offM0 = (((c0 + 0) * H_ + yy0) * W_ + x0) * 4;
  int offM1 = offM0 + HW * 4;
  int offM2 = offM1 + HW * 4;
  int offM3 = offM2 + HW * 4;
  int offA0 = mA ? offM0 - 16 : offM0;
  int offA1 = mA ? offM1 - 16 : offM1;
  int offA2 = mA ? offM2 - 16 : offM2;
  int offA3 = mA ? offM3 - 16 : offM3;
  int offE0 = mE ? offM0 + 16 : offM0;
  int offE1 = mE ? offM1 + 16 : offM1;
  int offE2 = mE ? offM2 + 16 : offM2;
  int offE3 = mE ? offM3 + 16 : offM3;

  // prologue: group-0 (ch c0,c0+1) loads in flight while staging drains
  float4 gA0 = LD(offA0), gM0 = LD(offM0), gE0 = LD(offE0);
  float4 gA1 = LD(offA1), gM1 = LD(offM1), gE1 = LD(offE1);

  __syncthreads();

  float acc0[4] = {0.f, 0.f, 0.f, 0.f};
  float acc1[4] = {0.f, 0.f, 0.f, 0.f};
  float acc2[4] = {0.f, 0.f, 0.f, 0.f};
  float acc3[4] = {0.f, 0.f, 0.f, 0.f};

  for (int p = pstart; p < pend; ++p) {
    float4 fo[DD];
#pragma unroll
    for (int o = 0; o < DD; ++o)
      fo[o] = *reinterpret_cast<const float4*>(&ldsF[(p * DD + o) * 64 + (xg << 2)]);

    // group-1 (ch c0+2,c0+3) loads for current p
    float4 hA0 = LD(offA2), hM0 = LD(offM2), hE0 = LD(offE2);
    float4 hA1 = LD(offA3), hM1 = LD(offM3), hE1 = LD(offE3);

    const int adv = (p + 1 < pend) ? (W_ * 4) : 0;   // uniform (SALU)

    FMA_GRP(acc0, gA0, gM0, gE0);
    FMA_GRP(acc1, gA1, gM1, gE1);

    offA0 += adv; offM0 += adv; offE0 += adv;
    offA1 += adv; offM1 += adv; offE1 += adv;

    // prefetch group-0 for next p
    gA0 = LD(offA0); gM0 = LD(offM0); gE0 = LD(offE0);
    gA1 = LD(offA1); gM1 = LD(offM1); gE1 = LD(offE1);

    offA2 += adv; offM2 += adv; offE2 += adv;
    offA3 += adv; offM3 += adv; offE3 += adv;

    FMA_GRP(acc2, hA0, hM0, hE0);
    FMA_GRP(acc3, hA1, hM1, hE1);
  }

  const float inv_c = 1.0f / (float)C_;
  float* outB = out + (size_t)b * C_ * HW + (size_t)y * W_ + x0;
  {
    float4 v;
    v.x = acc0[0] * inv_c; v.y = acc0[1] * inv_c;
    v.z = acc0[2] * inv_c; v.w = acc0[3] * inv_c;
    *reinterpret_cast<float4*>(outB + (size_t)(c0 + 0) * HW) = v;
    v.x = acc1[0] * inv_c; v.y = acc1[1] * inv_c;
    v.z = acc1[2] * inv_c; v.w = acc1[3] * inv_c;
    *reinterpret_cast<float4*>(outB + (size_t)(c0 + 1) * HW) = v;
    v.x = acc2[0] * inv_c; v.y = acc2[1] * inv_c;
    v.z = acc2[2] * inv_c; v.w = acc2[3] * inv_c;
    *reinterpret_cast<float4*>(outB + (size_t)(c0 + 2) * HW) = v;
    v.x = acc3[0] * inv_c; v.y = acc3[1] * inv_c;
    v.z = acc3[2] * inv_c; v.w = acc3[3] * inv_c;
    *reinterpret_cast<float4*>(outB + (size_t)(c0 + 3) * HW) = v;
  }
}

extern "C" void kernel_launch(void* const* d_in, const int* in_sizes, int n_in,
                              void* d_out, int out_size, void* d_ws, size_t ws_size,
                              hipStream_t stream) {
  const float* first  = (const float*)d_in[0];
  const float* second = (const float*)d_in[1];
  float* out = (float*)d_out;

  corr_transpose_kernel<<<dim3(NWG), 256, 0, stream>>>(first, second, out);
}

// Round 6
// 127.019 us; speedup vs baseline: 1.0540x; 1.0540x over previous
//
#include <hip/hip_runtime.h>

#define MD 4
#define DD 9          // 2*MD+1
#define KK 81         // DD*DD
#define B_ 4
#define C_ 128
#define H_ 192
#define W_ 192
#define HW (H_ * W_)
#define NWG 4608      // 2 chalf * 3 xt * 192 y * 4 b
#define PER_XCD (NWG / 8)

// out[b,c,y,x] = (1/C) * sum_{p,o} first[b,p*9+o,y,x] * second[b,c,y+p-4,x+o-4]
//
// Round 6 = round-4 kernel (90.6us, proven) + ONE change: X-edge handling
// folded into the weights at LDS-stage time (ldsF[k][xl] multiplies
// second[x = xt0+xl+(k%9)-4]; zero it once if OOB). Deletes 288
// v_cndmask/thread in 2/3 of blocks. Edge s-loads stay clamped in-bounds;
// garbage * 0 = correct (round 5 verified numerics: absmax unchanged).
//
// DO NOT touch the 64-bit per-lane pointer math or load placement: round 5's
// 32-bit-offset rewrite dropped VGPR 72->60, the allocator sank the loads,
// the software pipeline collapsed (VALUBusy 39->29%, dur 90.6->134us).
// (256,1): no VGPR pin. Spill sentinel: WRITE_SIZE must stay == 73728 KB.

__device__ __forceinline__ void unpack12(float (&s)[12],
                                         const float4& A, const float4& M,
                                         const float4& E) {
  s[0] = A.x; s[1] = A.y; s[2]  = A.z; s[3]  = A.w;
  s[4] = M.x; s[5] = M.y; s[6]  = M.z; s[7]  = M.w;
  s[8] = E.x; s[9] = E.y; s[10] = E.z; s[11] = E.w;
}

#define FMA_GROUP(accp, s)                                   \
  _Pragma("unroll")                                          \
  for (int o = 0; o < DD; ++o) {                             \
    accp[0] = fmaf(fo[o].x, s[o + 0], accp[0]);              \
    accp[1] = fmaf(fo[o].y, s[o + 1], accp[1]);              \
    accp[2] = fmaf(fo[o].z, s[o + 2], accp[2]);              \
    accp[3] = fmaf(fo[o].w, s[o + 3], accp[3]);              \
  }

__global__ __launch_bounds__(256, 1)
void corr_transpose_kernel(const float* __restrict__ first,
                           const float* __restrict__ second,
                           float* __restrict__ out) {
  __shared__ __align__(16) float ldsF[KK * 64];

  // bijective XCD swizzle (4608 % 8 == 0), y-fastest within an XCD chunk
  const int lin = blockIdx.x;
  const int wid = (lin & 7) * PER_XCD + (lin >> 3);
  const int y     = wid % H_;
  const int t     = wid / H_;          // 0..23
  const int chalf = t & 1;
  const int xt0   = ((t >> 1) % 3) * 64;
  const int b     = t / 6;

  const int tid = threadIdx.x;

  // ---- stage first[b,:,y,xt0..+63] into LDS with X-edge weight masking ----
  {
    const float* fbase = first + ((size_t)(b * KK) * H_ + y) * (size_t)W_ + xt0;
    const bool edge = (xt0 != 64);     // block-uniform
    for (int idx = tid; idx < KK * 16; idx += 256) {
      const int k  = idx >> 4;
      const int xi = (idx & 15) << 2;
      float4 v = *reinterpret_cast<const float4*>(fbase + (size_t)k * HW + xi);
      if (edge) {
        const int o    = k % DD;
        const int base = xt0 + xi + o - MD;   // second-x for component 0
        if (base + 0 < 0 || base + 0 >= W_) v.x = 0.f;
        if (base + 1 < 0 || base + 1 >= W_) v.y = 0.f;
        if (base + 2 < 0 || base + 2 >= W_) v.z = 0.f;
        if (base + 3 < 0 || base + 3 >= W_) v.w = 0.f;
      }
      *reinterpret_cast<float4*>(&ldsF[k * 64 + xi]) = v;
    }
  }

  const int xg = tid & 15;
  const int cg = tid >> 4;
  const int c0 = chalf * 64 + cg * 4;
  const int x0 = xt0 + xg * 4;

  // clamped per-lane offsets; OOB float4s have zeroed weights in LDS
  const bool mA = (x0 != 0);
  const bool mE = (x0 + 8 <= W_);
  const int  oa = mA ? x0 - 4 : 0;
  const int  oe = mE ? x0 + 4 : W_ - 8;

  // p-loop bounds hoisted (block-uniform)
  const int pstart = (y >= MD) ? 0 : (MD - y);
  const int pend   = (y + MD < H_) ? DD : (H_ + MD - y);
  const int yy0    = y + pstart - MD;

  const float* secB = second + (size_t)b * C_ * HW;
  const float* rp0 = secB + ((size_t)c0 * H_ + yy0) * (size_t)W_;
  const float* rp1 = rp0 + HW;
  const float* rp2 = rp1 + HW;
  const float* rp3 = rp2 + HW;

  // prologue: group-0 loads in flight while LDS staging drains
  float4 gA0 = *reinterpret_cast<const float4*>(rp0 + oa);
  float4 gM0 = *reinterpret_cast<const float4*>(rp0 + x0);
  float4 gE0 = *reinterpret_cast<const float4*>(rp0 + oe);
  float4 gA1 = *reinterpret_cast<const float4*>(rp1 + oa);
  float4 gM1 = *reinterpret_cast<const float4*>(rp1 + x0);
  float4 gE1 = *reinterpret_cast<const float4*>(rp1 + oe);

  __syncthreads();

  float acc0[4] = {0.f, 0.f, 0.f, 0.f};
  float acc1[4] = {0.f, 0.f, 0.f, 0.f};
  float acc2[4] = {0.f, 0.f, 0.f, 0.f};
  float acc3[4] = {0.f, 0.f, 0.f, 0.f};

  for (int p = pstart; p < pend; ++p) {
    float4 fo[DD];
#pragma unroll
    for (int o = 0; o < DD; ++o)
      fo[o] = *reinterpret_cast<const float4*>(&ldsF[(p * DD + o) * 64 + (xg << 2)]);

    // issue group-1 loads (current p) before consuming group 0
    float4 hA0 = *reinterpret_cast<const float4*>(rp2 + oa);
    float4 hM0 = *reinterpret_cast<const float4*>(rp2 + x0);
    float4 hE0 = *reinterpret_cast<const float4*>(rp2 + oe);
    float4 hA1 = *reinterpret_cast<const float4*>(rp3 + oa);
    float4 hM1 = *reinterpret_cast<const float4*>(rp3 + x0);
    float4 hE1 = *reinterpret_cast<const float4*>(rp3 + oe);

    {  // FMA group 0 (channels c0, c0+1)
      float s[12];
      unpack12(s, gA0, gM0, gE0);
      FMA_GROUP(acc0, s);
      float u[12];
      unpack12(u, gA1, gM1, gE1);
      FMA_GROUP(acc1, u);
    }

    // advance rows (clamped on last iter: dead but in-bounds reload)
    const int adv = (p + 1 < pend) ? W_ : 0;
    rp0 += adv; rp1 += adv; rp2 += adv; rp3 += adv;

    // prefetch group-0 for next p
    gA0 = *reinterpret_cast<const float4*>(rp0 + oa);
    gM0 = *reinterpret_cast<const float4*>(rp0 + x0);
    gE0 = *reinterpret_cast<const float4*>(rp0 + oe);
    gA1 = *reinterpret_cast<const float4*>(rp1 + oa);
    gM1 = *reinterpret_cast<const float4*>(rp1 + x0);
    gE1 = *reinterpret_cast<const float4*>(rp1 + oe);

    {  // FMA group 1 (channels c0+2, c0+3)
      float s[12];
      unpack12(s, hA0, hM0, hE0);
      FMA_GROUP(acc2, s);
      float u[12];
      unpack12(u, hA1, hM1, hE1);
      FMA_GROUP(acc3, u);
    }
  }

  const float inv_c = 1.0f / (float)C_;
  float* outB = out + (size_t)b * C_ * HW + (size_t)y * W_ + x0;
  {
    float4 v;
    v.x = acc0[0] * inv_c; v.y = acc0[1] * inv_c;
    v.z = acc0[2] * inv_c; v.w = acc0[3] * inv_c;
    *reinterpret_cast<float4*>(outB + (size_t)(c0 + 0) * HW) = v;
    v.x = acc1[0] * inv_c; v.y = acc1[1] * inv_c;
    v.z = acc1[2] * inv_c; v.w = acc1[3] * inv_c;
    *reinterpret_cast<float4*>(outB + (size_t)(c0 + 1) * HW) = v;
    v.x = acc2[0] * inv_c; v.y = acc2[1] * inv_c;
    v.z = acc2[2] * inv_c; v.w = acc2[3] * inv_c;
    *reinterpret_cast<float4*>(outB + (size_t)(c0 + 2) * HW) = v;
    v.x = acc3[0] * inv_c; v.y = acc3[1] * inv_c;
    v.z = acc3[2] * inv_c; v.w = acc3[3] * inv_c;
    *reinterpret_cast<float4*>(outB + (size_t)(c0 + 3) * HW) = v;
  }
}

extern "C" void kernel_launch(void* const* d_in, const int* in_sizes, int n_in,
                              void* d_out, int out_size, void* d_ws, size_t ws_size,
                              hipStream_t stream) {
  const float* first  = (const float*)d_in[0];
  const float* second = (const float*)d_in[1];
  float* out = (float*)d_out;

  corr_transpose_kernel<<<dim3(NWG), 256, 0, stream>>>(first, second, out);
}